// Round 2
// baseline (302.612 us; speedup 1.0000x reference)
//
#include <hip/hip_runtime.h>
#include <stdint.h>

#define BATCH   32
#define ROWS    4096
#define COLS    256
#define COL_IDX 5

typedef unsigned long long u64;
typedef unsigned int       u32;

// ---------------------------------------------------------------------------
// Kernel 1: extract column COL_IDX, pack into order-preserving u64 keys.
//   t = ~(order_preserving_uint(f))  -> ascending u64 sort == descending float
//   low 32 bits = row index          -> all keys distinct, stable tie-break
// ---------------------------------------------------------------------------
__global__ __launch_bounds__(256)
void extract_keys_kernel(const float* __restrict__ x, u64* __restrict__ keys) {
    const int i = blockIdx.x * 256 + threadIdx.x;      // 0 .. BATCH*ROWS-1
    u32 u = __float_as_uint(x[(size_t)i * COLS + COL_IDX]);
    u = (u >> 31) ? ~u : (u | 0x80000000u);            // order-preserving map
    u = ~u;                                            // descending
    keys[i] = ((u64)u << 32) | (u32)(i & (ROWS - 1));
}

// ---------------------------------------------------------------------------
// Kernel 2: rank-by-counting + fused row copy.
// One wave owns 64 consecutive source rows of one batch. Rank of row i =
// #{j : packed[j] < packed[i]} (exact permutation, keys distinct).
// Broadcast of compared keys via v_readlane (VALU pipe, immediate lane index
// from the unrolled loop) — NOT __shfl, which lowers to ds_bpermute (LDS pipe)
// and would serialize against 8 waves/CU.
// Then the wave copies row r0+l -> out row rank[l]: one float4/lane = 1 KB/row.
// ---------------------------------------------------------------------------
__global__ __launch_bounds__(256)
void rank_copy_kernel(const float* __restrict__ x,
                      const u64* __restrict__ keys,
                      float* __restrict__ out) {
    const int wave = blockIdx.x * 4 + ((int)threadIdx.x >> 6);
    const int lane = (int)threadIdx.x & 63;
    const int b    = wave >> 6;                 // 64 waves per batch
    const int r0   = (wave & 63) << 6;          // first of this wave's 64 rows
    const u64* kb  = keys + (size_t)b * ROWS;

    const u64 my = kb[r0 + lane];
    int rank = 0;
    for (int j0 = 0; j0 < ROWS; j0 += 64) {
        const u64 kv = kb[j0 + lane];           // 64 keys, coalesced
        const u32 lo = (u32)kv, hi = (u32)(kv >> 32);
        #pragma unroll
        for (int l = 0; l < 64; ++l) {
            const u32 klo = (u32)__builtin_amdgcn_readlane(lo, l);
            const u32 khi = (u32)__builtin_amdgcn_readlane(hi, l);
            const u64 kk  = ((u64)khi << 32) | klo;
            rank += (kk < my) ? 1 : 0;
        }
    }

    // Copy 64 rows: row (r0+l) -> output row rank-of-(r0+l).
    const float4* src  = (const float4*)(x   + ((size_t)b * ROWS + r0) * COLS);
    float4*       outb = (float4*)      (out + (size_t)b * ROWS * COLS);
    #pragma unroll 8
    for (int l = 0; l < 64; ++l) {
        const int dst = __builtin_amdgcn_readlane(rank, l);   // uniform
        outb[(size_t)dst * 64 + lane] = src[l * 64 + lane];
    }
}

extern "C" void kernel_launch(void* const* d_in, const int* in_sizes, int n_in,
                              void* d_out, int out_size, void* d_ws, size_t ws_size,
                              hipStream_t stream) {
    const float* x   = (const float*)d_in[0];
    float*       out = (float*)d_out;
    u64*         keys = (u64*)d_ws;            // BATCH*ROWS*8 = 1 MB scratch

    extract_keys_kernel<<<(BATCH * ROWS) / 256, 256, 0, stream>>>(x, keys);
    rank_copy_kernel<<<(BATCH * ROWS) / 256, 256, 0, stream>>>(x, keys, out);
}